// Round 7
// baseline (2933.600 us; speedup 1.0000x reference)
//
#include <hip/hip_runtime.h>

// ---------------------------------------------------------------------------
// MozafariMNIST2018 SNN forward — INSTRUMENTATION ROUND.
// Each kernel inner-repeats `reps` times (idempotent) so every dispatch
// exceeds the ~120us harness poison fills and surfaces in rocprof top-5
// with full counters. Per-rep dur = dispatch_dur / reps.
// ---------------------------------------------------------------------------

typedef unsigned short u16;
typedef __attribute__((ext_vector_type(8))) short short8;
typedef __attribute__((ext_vector_type(4))) float f32x4;
typedef __attribute__((ext_vector_type(4))) float float4v;

#define T_STEPS 15

// ws layout (byte offsets), all 16B aligned
#define WHI_OFF     0u
#define WLO_OFF     147456u
#define SPKIN_OFF   294912u
#define MAXV_OFF    6346512u
#define ARGM_OFF    6730512u
#define WINMAP_OFF  7114512u
#define POTWIN_OFF  7140112u

#define N_CONV1  1500
#define N_PREP   288
#define N_BORDER 18

static __device__ __forceinline__ u16 f2bf_rne(float f) {
  unsigned u = __float_as_uint(f);
  unsigned r = u + 0x7FFFu + ((u >> 16) & 1u);
  return (u16)(r >> 16);
}
static __device__ __forceinline__ float bf2f(u16 b) {
  return __uint_as_float(((unsigned)b) << 16);
}

// ---------------------------------------------------------------------------
__global__ __launch_bounds__(256) void fill_kernel(float4v* __restrict__ p,
                                                   int n4, int reps) {
  int i0 = blockIdx.x * 256 + threadIdx.x;
  int stride = gridDim.x * 256;
  float4v z = {0.f, 0.f, 0.f, 0.f};
  for (int rep = 0; rep < reps; ++rep) {
    asm volatile("" ::: "memory");
    for (int i = i0; i < n4; i += stride) p[i] = z;
  }
}

// ---------------------------------------------------------------------------
// conv1 (MFMA) + prep_wt + spk_in border, block-partitioned.
__global__ __launch_bounds__(256) void conv1x_kernel(
    const int* __restrict__ xin, const float* __restrict__ w1,
    const float* __restrict__ w2, u16* __restrict__ spk_in,
    u16* __restrict__ Whi, u16* __restrict__ Wlo, int reps) {
  __shared__ u16 w1s[32 * 160];
  __shared__ u16 patch[6 * 20 * 20 + 320];
  __shared__ unsigned char fires[30 * 256];

  int tid = threadIdx.x;
  int b = blockIdx.x;

  for (int rep = 0; rep < reps; ++rep) {
    asm volatile("" ::: "memory");
    if (b >= N_CONV1) {
      if (b < N_CONV1 + N_PREP) {
        int g = (b - N_CONV1) * 256 + tid;   // < 73728
        int f = g / 288, k = g % 288;
        u16 h = 0, l = 0;
        if (f < 250 && k < 270) {
          float w = w2[f * 270 + k];
          h = f2bf_rne(w);
          l = f2bf_rne(w - bf2f(h));
        }
        Whi[g] = h;
        Wlo[g] = l;
      } else {
        int idx = (b - N_CONV1 - N_PREP) * 256 + tid;
        for (int u = idx; u < 145800; u += N_BORDER * 256) {
          int tc = u / 324, i = u % 324;
          int row, col;
          if (i < 82) { row = 0; col = i; }
          else if (i < 164) { row = 81; col = i - 82; }
          else if (i < 244) { row = 1 + (i - 164); col = 0; }
          else { row = 1 + (i - 244); col = 81; }
          spk_in[(size_t)tc * 6724 + row * 82 + col] = 0;
        }
      }
      continue;
    }

    int t = b / 100, tile = b % 100;
    int ty0 = (tile / 10) * 16, tx0 = (tile % 10) * 16;

    for (int idx = tid; idx < 32 * 160; idx += 256) {
      int f = idx / 160, k = idx % 160;
      w1s[idx] = (f < 30 && k < 150) ? f2bf_rne(w1[f * 150 + k]) : (u16)0;
    }
    for (int idx = tid; idx < 2720; idx += 256) {
      u16 v = 0;
      if (idx < 2400) {
        int c = idx / 400, rem = idx % 400;
        int r = rem / 20, col = rem % 20;
        int gy = ty0 + r - 2, gx = tx0 + col - 2;
        if ((unsigned)gy < 160u && (unsigned)gx < 160u)
          v = xin[((t * 6 + c) * 160 + gy) * 160 + gx] ? (u16)0x3F80 : (u16)0;
      }
      patch[idx] = v;
    }
    __syncthreads();

    int lane = tid & 63, wave = tid >> 6;
    int lrow = lane & 15, lgrp = lane >> 4;

    short8 afr[2][5];
#pragma unroll
    for (int m = 0; m < 2; ++m)
#pragma unroll
      for (int ks = 0; ks < 5; ++ks)
        afr[m][ks] =
            *(const short8*)&w1s[(m * 16 + lrow) * 160 + ks * 32 + lgrp * 8];

    int offs[5][8];
#pragma unroll
    for (int ks = 0; ks < 5; ++ks)
#pragma unroll
      for (int j = 0; j < 8; ++j) {
        int k = ks * 32 + lgrp * 8 + j;
        if (k < 150) {
          int c = k / 25, r = k % 25, ky = r / 5, kx = r % 5;
          offs[ks][j] = c * 400 + ky * 20 + kx;
        } else {
          offs[ks][j] = 2400;
        }
      }

    for (int ph = 0; ph < 4; ++ph) {
      int rrow = ph * 4 + wave;
      int pbase = rrow * 20 + lrow;
      short8 bfr[5];
#pragma unroll
      for (int ks = 0; ks < 5; ++ks)
#pragma unroll
        for (int j = 0; j < 8; ++j)
          bfr[ks][j] = (short)patch[offs[ks][j] + pbase];
      f32x4 acc0 = {0.f, 0.f, 0.f, 0.f}, acc1 = {0.f, 0.f, 0.f, 0.f};
#pragma unroll
      for (int ks = 0; ks < 5; ++ks) {
        acc0 = __builtin_amdgcn_mfma_f32_16x16x32_bf16(afr[0][ks], bfr[ks],
                                                       acc0, 0, 0, 0);
        acc1 = __builtin_amdgcn_mfma_f32_16x16x32_bf16(afr[1][ks], bfr[ks],
                                                       acc1, 0, 0, 0);
      }
#pragma unroll
      for (int r = 0; r < 4; ++r) {
        int f0 = lgrp * 4 + r;
        fires[f0 * 256 + rrow * 16 + lrow] = (acc0[r] >= 15.f);
        int f1 = 16 + lgrp * 4 + r;
        if (f1 < 30) fires[f1 * 256 + rrow * 16 + lrow] = (acc1[r] >= 15.f);
      }
    }
    __syncthreads();

    int pby0 = (ty0 >> 1) + 1, pbx0 = (tx0 >> 1) + 1;
    for (int idx = tid; idx < 30 * 64; idx += 256) {
      int f = idx >> 6, pp = idx & 63;
      int py = pp >> 3, px = pp & 7;
      const unsigned char* fb = &fires[f * 256 + py * 32 + px * 2];
      int v = fb[0] | fb[1] | fb[16] | fb[17];
      spk_in[((t * 30 + f) * 82 + pby0 + py) * 82 + pbx0 + px] =
          v ? (u16)0x3F80 : (u16)0;
    }
    __syncthreads();
  }
}

// ---------------------------------------------------------------------------
// conv2 implicit-GEMM MFMA (R6 unrolled + weight reg-dbuf), inner-repeated.
__global__ __launch_bounds__(256) void conv2_kernel(
    const u16* __restrict__ spk_in, const u16* __restrict__ Whi,
    const u16* __restrict__ Wlo, float* __restrict__ maxv_ws,
    int* __restrict__ argm_ws, int reps) {
  __shared__ __align__(16) u16 lds[64 * 320 + 3008];
  u16* Xt = lds;
  u16* patch = lds + 20480;

  int tid = threadIdx.x;
  int b = blockIdx.x;
  int t = b / 100, tile = b % 100;
  int y0 = (tile / 10) * 8, x0 = (tile % 10) * 8;

  for (int rep = 0; rep < reps; ++rep) {
    asm volatile("" ::: "memory");
    const u16* sb = spk_in + (size_t)t * 30 * 6724;
    for (int idx = tid; idx < 3000; idx += 256) {
      int c = idx / 100, rem = idx % 100;
      int dy = rem / 10, dx = rem % 10;
      patch[idx] = sb[c * 6724 + (y0 + dy) * 82 + (x0 + dx)];
    }
    __syncthreads();

    for (int task = tid; task < 2304; task += 256) {
      int p = task / 36, g = task % 36;
      int py = p >> 3, px = p & 7;
      short8 sv;
#pragma unroll
      for (int j = 0; j < 8; ++j) {
        int k = g * 8 + j;
        u16 v = 0;
        if (k < 270) {
          int c = k / 9, r9 = k % 9;
          int ky = r9 / 3, kx = r9 % 3;
          v = patch[(c * 10 + py + ky) * 10 + (px + kx)];
        }
        sv[j] = (short)v;
      }
      int off = (p * 320 + g * 8) ^ ((p & 7) << 3);
      *(short8*)(Xt + off) = sv;
    }
    __syncthreads();

    int lane = tid & 63, wave = tid >> 6;
    int lrow = lane & 15, lgrp = lane >> 4;
    int fbase = wave * 64;

    f32x4 acc[4][4];
#pragma unroll
    for (int i = 0; i < 4; ++i)
#pragma unroll
      for (int j = 0; j < 4; ++j) acc[i][j] = (f32x4){0.f, 0.f, 0.f, 0.f};

    const u16* whib = Whi + (fbase + lrow) * 288 + lgrp * 8;
    const u16* wlob = Wlo + (fbase + lrow) * 288 + lgrp * 8;
    int xorr = (lrow & 7) << 3;

    short8 ah[2][4], al[2][4];
#pragma unroll
    for (int ft = 0; ft < 4; ++ft) {
      ah[0][ft] = *(const short8*)(whib + ft * 16 * 288);
      al[0][ft] = *(const short8*)(wlob + ft * 16 * 288);
    }

#pragma unroll
    for (int ks = 0; ks < 9; ++ks) {
      int cur = ks & 1, nxt = cur ^ 1;
      if (ks < 8) {
#pragma unroll
        for (int ft = 0; ft < 4; ++ft) {
          ah[nxt][ft] =
              *(const short8*)(whib + ft * 16 * 288 + (ks + 1) * 32);
          al[nxt][ft] =
              *(const short8*)(wlob + ft * 16 * 288 + (ks + 1) * 32);
        }
      }
      short8 bfr[4];
#pragma unroll
      for (int pt = 0; pt < 4; ++pt) {
        int s = ((pt * 16 + lrow) * 320 + ks * 32 + lgrp * 8) ^ xorr;
        bfr[pt] = *(const short8*)(Xt + s);
      }
#pragma unroll
      for (int ft = 0; ft < 4; ++ft)
#pragma unroll
        for (int pt = 0; pt < 4; ++pt) {
          acc[ft][pt] = __builtin_amdgcn_mfma_f32_16x16x32_bf16(
              ah[cur][ft], bfr[pt], acc[ft][pt], 0, 0, 0);
          acc[ft][pt] = __builtin_amdgcn_mfma_f32_16x16x32_bf16(
              al[cur][ft], bfr[pt], acc[ft][pt], 0, 0, 0);
        }
    }

    __syncthreads();
    float* redv = (float*)lds;
    int*   redi = (int*)(lds + 512);

#pragma unroll
    for (int pt = 0; pt < 4; ++pt) {
      float bv = -1.f; int bf = 0;
#pragma unroll
      for (int ft = 0; ft < 4; ++ft)
#pragma unroll
        for (int r = 0; r < 4; ++r) {
          float v = acc[ft][pt][r];
          v = (v >= 10.f) ? v : 0.f;
          int f = fbase + ft * 16 + lgrp * 4 + r;
          if (v > bv) { bv = v; bf = f; }
        }
      {
        float ov = __shfl_xor(bv, 16); int of = __shfl_xor(bf, 16);
        if (ov > bv || (ov == bv && of < bf)) { bv = ov; bf = of; }
        ov = __shfl_xor(bv, 32); of = __shfl_xor(bf, 32);
        if (ov > bv || (ov == bv && of < bf)) { bv = ov; bf = of; }
      }
      if (lgrp == 0) {
        redv[wave * 64 + pt * 16 + lrow] = bv;
        redi[wave * 64 + pt * 16 + lrow] = bf;
      }
    }
    __syncthreads();
    if (tid < 64) {
      float bv = -1.f; int bf = 0x7fffffff;
#pragma unroll
      for (int w = 0; w < 4; ++w) {
        float v = redv[w * 64 + tid]; int f = redi[w * 64 + tid];
        if (v > bv || (v == bv && f < bf)) { bv = v; bf = f; }
      }
      int pos = (y0 + (tid >> 3)) * 80 + x0 + (tid & 7);
      maxv_ws[t * 6400 + pos] = bv;
      argm_ws[t * 6400 + pos] = bf;
    }
    __syncthreads();
  }
}

// ---------------------------------------------------------------------------
__global__ __launch_bounds__(256) void recompute_kernel(
    const u16* __restrict__ spk_in, const float* __restrict__ w2,
    const float* __restrict__ maxv, const int* __restrict__ argm,
    int* __restrict__ winmap, float* __restrict__ potwin, int reps) {
  __shared__ u16 patch[30 * 18 * 18];

  int tid = threadIdx.x;
  int b = blockIdx.x;
  int t = b / 25, tile = b % 25;
  int ty0 = (tile / 5) * 16, tx0 = (tile % 5) * 16;

  for (int rep = 0; rep < reps; ++rep) {
    asm volatile("" ::: "memory");
    const u16* base = spk_in + (size_t)t * 30 * 6724;
    for (int idx = tid; idx < 9720; idx += 256) {
      int c = idx / 324, rem = idx % 324;
      int dy = rem / 18, dx = rem % 18;
      patch[idx] = base[c * 6724 + (ty0 + dy) * 82 + (tx0 + dx)];
    }

    int py = tid >> 4, px = tid & 15;
    int pos = (ty0 + py) * 80 + tx0 + px;

    int nc = 0;
#pragma unroll
    for (int tt = 0; tt < T_STEPS; ++tt)
      nc += (maxv[tt * 6400 + pos] > 0.f) ? 1 : 0;
    int e = T_STEPS - nc; if (e > 14) e = 14;
    int win = argm[e * 6400 + pos];
    bool gate = maxv[14 * 6400 + pos] > 0.f;
    win = gate ? win : -1;
    if (t == 0) winmap[pos] = win;

    __syncthreads();

    float p = 0.f;
    if (win >= 0) {
      const float* wt = w2 + win * 270;
      float a = 0.f;
      for (int c = 0; c < 30; ++c) {
#pragma unroll
        for (int ky = 0; ky < 3; ++ky)
#pragma unroll
          for (int kx = 0; kx < 3; ++kx)
            a = fmaf(wt[c * 9 + ky * 3 + kx],
                     bf2f(patch[c * 324 + (py + ky) * 18 + (px + kx)]), a);
      }
      p = (a >= 10.f) ? a : 0.f;
    }
    potwin[t * 6400 + pos] = p;
    __syncthreads();
  }
}

// ---------------------------------------------------------------------------
__global__ __launch_bounds__(1024) void finalize_kernel(
    const int* __restrict__ winmap, const float* __restrict__ potwin,
    float* __restrict__ out, float* __restrict__ out_win, int reps) {
  __shared__ float tv[6400];
  __shared__ int   tf[6400];
  __shared__ float wv_s[16];
  __shared__ int   wk_s[16];
  __shared__ int   sh_w[4];
  __shared__ float vmax_s;

  int tid = threadIdx.x;
  int b = blockIdx.x;

  for (int rep = 0; rep < reps; ++rep) {
    asm volatile("" ::: "memory");
    if (b > 0) {
      int pos = (b - 1) * 256 + (tid & 255);
      int tq = tid >> 8;
      int win = winmap[pos];
      if (win >= 0) {
        int tend = tq * 4 + 4; if (tend > T_STEPS) tend = T_STEPS;
        for (int t = tq * 4; t < tend; ++t) {
          float p = potwin[t * 6400 + pos];
          int o = (t * 250 + win) * 6400 + pos;
          out[o] = (p > 0.f) ? 1.f : 0.f;
          out[24000000 + o] = p;
        }
      }
      continue;
    }

    int lane = tid & 63, wid = tid >> 6;

    float localmax = 0.f;
    for (int pos = tid; pos < 6400; pos += 1024) {
      int win = winmap[pos];
      float val = 0.f; int nspk = 0;
      if (win >= 0) {
#pragma unroll
        for (int t = 0; t < T_STEPS; ++t)
          nspk += (potwin[t * 6400 + pos] > 0.f) ? 1 : 0;
        int first = T_STEPS - nspk; if (first > 14) first = 14;
        val = potwin[first * 6400 + pos];
        if (nspk > 0 && val > localmax) localmax = val;
      }
      tv[pos] = val;
      tf[pos] = ((win + 1) << 4) | nspk;
    }
#pragma unroll
    for (int m = 1; m < 64; m <<= 1)
      localmax = fmaxf(localmax, __shfl_xor(localmax, m));
    if (lane == 0) wv_s[wid] = localmax;
    __syncthreads();
    if (tid == 0) {
      float m = 0.f;
#pragma unroll
      for (int w = 0; w < 16; ++w) m = fmaxf(m, wv_s[w]);
      vmax_s = m * (float)T_STEPS;
    }
    __syncthreads();
    float v = vmax_s;

    for (int pos = tid; pos < 6400; pos += 1024) {
      int meta = tf[pos];
      int win = (meta >> 4) - 1, nspk = meta & 15;
      tf[pos] = win;
      tv[pos] = (win >= 0) ? (float)nspk * (tv[pos] + v) : 0.f;
    }
    __syncthreads();

    for (int it = 0; it < 8; ++it) {
      float bv = -1.f; int bk = 0x7fffffff;
      for (int pos = tid; pos < 6400; pos += 1024) {
        float tvv = tv[pos];
        int key = tf[pos] * 6400 + pos;
        if (tvv > bv || (tvv == bv && key < bk)) { bv = tvv; bk = key; }
      }
#pragma unroll
      for (int m = 1; m < 64; m <<= 1) {
        float ov = __shfl_xor(bv, m); int ok = __shfl_xor(bk, m);
        if (ov > bv || (ov == bv && ok < bk)) { bv = ov; bk = ok; }
      }
      if (lane == 0) { wv_s[wid] = bv; wk_s[wid] = bk; }
      __syncthreads();
      if (tid == 0) {
        float mbv = -1.f; int mbk = 0x7fffffff;
#pragma unroll
        for (int w = 0; w < 16; ++w) {
          float ov = wv_s[w]; int ok = wk_s[w];
          if (ov > mbv || (ov == mbv && ok < mbk)) { mbv = ov; mbk = ok; }
        }
        int f = -1, r = -1, c = -1, valid = 0;
        if (mbv != 0.f) {
          f = mbk / 6400; int pos = mbk % 6400;
          r = pos / 80; c = pos % 80;
          valid = 1;
        }
        out_win[it * 3 + 0] = (float)f;
        out_win[it * 3 + 1] = (float)r;
        out_win[it * 3 + 2] = (float)c;
        sh_w[0] = f; sh_w[1] = r; sh_w[2] = c; sh_w[3] = valid;
      }
      __syncthreads();
      if (sh_w[3]) {
        int wf = sh_w[0], wr = sh_w[1], wc = sh_w[2];
        for (int pos = tid; pos < 6400; pos += 1024) {
          int r = pos / 80, c = pos % 80;
          int dr = r - wr; if (dr < 0) dr = -dr;
          int dc = c - wc; if (dc < 0) dc = -dc;
          if (tf[pos] == wf || (dr <= 1 && dc <= 1)) tv[pos] = 0.f;
        }
      }
      __syncthreads();
    }
    __syncthreads();
  }
}

// ---------------------------------------------------------------------------
extern "C" void kernel_launch(void* const* d_in, const int* in_sizes, int n_in,
                              void* d_out, int out_size, void* d_ws,
                              size_t ws_size, hipStream_t stream) {
  const int*   xin = (const int*)d_in[0];
  const float* w1  = (const float*)d_in[1];
  const float* w2  = (const float*)d_in[2];
  float* out = (float*)d_out;
  char*  ws  = (char*)d_ws;

  u16*   Whi    = (u16*)(ws + WHI_OFF);
  u16*   Wlo    = (u16*)(ws + WLO_OFF);
  u16*   spk_in = (u16*)(ws + SPKIN_OFF);
  float* maxv   = (float*)(ws + MAXV_OFF);
  int*   argm   = (int*)(ws + ARGM_OFF);
  int*   winmap = (int*)(ws + WINMAP_OFF);
  float* potwin = (float*)(ws + POTWIN_OFF);

  fill_kernel<<<2048, 256, 0, stream>>>((float4v*)d_out, out_size / 4, 5);
  conv1x_kernel<<<N_CONV1 + N_PREP + N_BORDER, 256, 0, stream>>>(
      xin, w1, w2, spk_in, Whi, Wlo, 24);
  conv2_kernel<<<1500, 256, 0, stream>>>(spk_in, Whi, Wlo, maxv, argm, 4);
  recompute_kernel<<<375, 256, 0, stream>>>(spk_in, w2, maxv, argm, winmap,
                                            potwin, 32);
  finalize_kernel<<<26, 1024, 0, stream>>>(winmap, potwin, out,
                                           out + 48000000, 32);
}

// Round 8
// 283.796 us; speedup vs baseline: 10.3370x; 10.3370x over previous
//
#include <hip/hip_runtime.h>

// ---------------------------------------------------------------------------
// MozafariMNIST2018 SNN forward (training branch, max_layer==2) for MI355X.
//
//  CHANNELS-LAST redesign: activations stored [t][y][x][c] so every MFMA
//  B-fragment is ONE contiguous 16B load (k = channel). No im2col, no LDS
//  staging, no K-loop barriers (R7 instrumentation: both convs were
//  issue-bound on scalar im2col gathers, MfmaUtil 3.2%).
//   K1a: repack xin->inp_cl | w1->w1cl | w2->Whi/Wlo (all channels-last)
//        | spk_cl border zeros
//   K1b: conv1-MFMA (direct-global B-frags) || d_out zero-fill
//   K2 : conv2-MFMA (direct-global A+B frags, 9 K-steps, LDS only f-reduce)
//   K3 : winmap + exact-fp32 recompute (w-hoisted 5-deep t-loop)
//   K4 : get_k_winners (block 0) || sparse scatter
//  All output values from exact fp32 recompute -> absmax 0.
// ---------------------------------------------------------------------------

typedef unsigned short u16;
typedef unsigned char u8;
typedef __attribute__((ext_vector_type(8))) short short8;
typedef __attribute__((ext_vector_type(4))) float f32x4;
typedef __attribute__((ext_vector_type(4))) float float4v;

#define T_STEPS 15

// ws byte offsets (all 16B aligned)
#define INPCL_OFF   0u          // 15*164*168*8 u16  = 6,612,480 B
#define SPKCL_OFF   6612480u    // 15*82*82*32 u16   = 6,455,040 B
#define W1CL_OFF    13067520u   // 10240 u16         = 20,480 B
#define WHI_OFF     13088000u   // 73728 u16         = 147,456 B
#define WLO_OFF     13235456u   // 147,456 B
#define MAXV_OFF    13382912u   // 96000 f32
#define ARGM_OFF    13766912u   // 96000 i32
#define WINMAP_OFF  14150912u   // 6400 i32
#define POTWIN_OFF  14176512u   // 96000 f32 -> end 14,560,512

// K1a block partition
#define NB_REPACK 1615
#define NB_W1     40
#define NB_W2     288
#define NB_BORD   76
#define K1A_GRID  (NB_REPACK + NB_W1 + NB_W2 + NB_BORD)

// K1b block partition
#define NB_CONV1  1500
#define NB_FILL   2048
#define K1B_GRID  (NB_CONV1 + NB_FILL)

static __device__ __forceinline__ u16 f2bf_rne(float f) {
  unsigned u = __float_as_uint(f);
  unsigned r = u + 0x7FFFu + ((u >> 16) & 1u);
  return (u16)(r >> 16);
}
static __device__ __forceinline__ float bf2f(u16 b) {
  return __uint_as_float(((unsigned)b) << 16);
}

// ---------------------------------------------------------------------------
// K1a: layout prep (channels-last everything) + spk_cl border ring zeros
__global__ __launch_bounds__(256) void prep_kernel(
    const int* __restrict__ xin, const float* __restrict__ w1,
    const float* __restrict__ w2, u16* __restrict__ inp_cl,
    u16* __restrict__ w1cl, u16* __restrict__ Whi, u16* __restrict__ Wlo,
    u16* __restrict__ spk_cl) {
  int tid = threadIdx.x, b = blockIdx.x;

  if (b < NB_REPACK) {
    // xin (15,6,160,160) int -> inp_cl[t][164][168][8] bf16 binary
    int g = b * 256 + tid;
    if (g < 413280) {
      int t = g / 27552, rem = g % 27552;
      int yy = rem / 168, xx = rem % 168;
      int y = yy - 2, x = xx - 2;
      short8 sv = {0, 0, 0, 0, 0, 0, 0, 0};
      if ((unsigned)y < 160u && (unsigned)x < 160u) {
        const int* xb = xin + ((size_t)t * 6 * 160 + y) * 160 + x;
#pragma unroll
        for (int c = 0; c < 6; ++c)
          sv[c] = xb[c * 25600] ? (short)0x3F80 : (short)0;
      }
      *(short8*)(inp_cl + (size_t)g * 8) = sv;
    }
  } else if (b < NB_REPACK + NB_W1) {
    // w1 (30,6,5,5) -> w1cl[f32][ky5][kxb2][dx4*c8]  (k = dx*8+c)
    int idx = (b - NB_REPACK) * 256 + tid;   // < 10240
    int f = idx / 320, r = idx % 320;
    int ky = r / 64, r2 = r % 64;
    int kxb = r2 >> 5, k = r2 & 31;
    int dx = k >> 3, c = k & 7;
    int kx = kxb * 4 + dx;
    u16 v = 0;
    if (f < 30 && c < 6 && kx < 5)
      v = f2bf_rne(w1[(f * 6 + c) * 25 + ky * 5 + kx]);
    w1cl[idx] = v;
  } else if (b < NB_REPACK + NB_W1 + NB_W2) {
    // w2 (250,30,3,3) -> Whi/Wlo[f256][kk9][c32] hi+lo bf16 split
    int g2 = (b - NB_REPACK - NB_W1) * 256 + tid;   // < 73728
    int f = g2 / 288, r = g2 % 288;
    int kk = r >> 5, c = r & 31;
    u16 h = 0, l = 0;
    if (f < 250 && c < 30) {
      float w = w2[f * 270 + c * 9 + kk];
      h = f2bf_rne(w);
      l = f2bf_rne(w - bf2f(h));
    }
    Whi[g2] = h;
    Wlo[g2] = l;
  } else {
    // spk_cl border ring zeros (pad of 82x82), 32 c per pos
    int u = (b - NB_REPACK - NB_W1 - NB_W2) * 256 + tid;
    if (u < 19440) {
      int pid = u >> 2, part = u & 3;
      int t = pid / 324, i = pid % 324;
      int row, col;
      if (i < 82) { row = 0; col = i; }
      else if (i < 164) { row = 81; col = i - 82; }
      else if (i < 244) { row = 1 + (i - 164); col = 0; }
      else { row = 1 + (i - 244); col = 81; }
      short8 z = {0, 0, 0, 0, 0, 0, 0, 0};
      *(short8*)(spk_cl + (((size_t)t * 82 + row) * 82 + col) * 32 +
                 part * 8) = z;
    }
  }
}

// ---------------------------------------------------------------------------
// K1b: conv1 MFMA (direct-global channels-last B-frags) || d_out zero fill.
// conv1 block: one t, 16x16 unpooled tile; 4 waves; wave w does rows
// {ph*4+w}; per row: 10 K-steps (5 ky x 2 kxb), K=32=(4dx x 8c).
__global__ __launch_bounds__(256) void conv1_fill_kernel(
    const u16* __restrict__ inp_cl, const u16* __restrict__ w1cl,
    u16* __restrict__ spk_cl, float4v* __restrict__ out4, int out_n4) {
  __shared__ u8 fires[30 * 256];
  __shared__ u16 pooled[64 * 32];

  int tid = threadIdx.x, b = blockIdx.x;

  if (b >= NB_CONV1) {
    int i = (b - NB_CONV1) * 256 + tid;
    float4v z = {0.f, 0.f, 0.f, 0.f};
    for (; i < out_n4; i += NB_FILL * 256) out4[i] = z;
    return;
  }

  int t = b / 100, tile = b % 100;
  int ty0 = (tile / 10) * 16, tx0 = (tile % 10) * 16;
  int lane = tid & 63, wave = tid >> 6, lrow = lane & 15, lgrp = lane >> 4;

  // hoist all 20 weight fragments (f = mt*16+lrow, k-sub = lgrp)
  short8 afr[2][10];
#pragma unroll
  for (int mt = 0; mt < 2; ++mt)
#pragma unroll
    for (int s = 0; s < 10; ++s)
      afr[mt][s] =
          *(const short8*)(w1cl + ((mt * 16 + lrow) * 10 + s) * 32 + lgrp * 8);

  const u16* ib = inp_cl + (size_t)t * 164 * 168 * 8;

  for (int ph = 0; ph < 4; ++ph) {
    int rrow = ph * 4 + wave;
    int oy = ty0 + rrow;
    f32x4 acc0 = {0.f, 0.f, 0.f, 0.f}, acc1 = {0.f, 0.f, 0.f, 0.f};
#pragma unroll
    for (int s = 0; s < 10; ++s) {
      int ky = s >> 1, kxb = s & 1;
      short8 bfr = *(const short8*)(
          ib + (((oy + ky) * 168) + tx0 + lrow + kxb * 4 + lgrp) * 8);
      acc0 = __builtin_amdgcn_mfma_f32_16x16x32_bf16(afr[0][s], bfr, acc0,
                                                     0, 0, 0);
      acc1 = __builtin_amdgcn_mfma_f32_16x16x32_bf16(afr[1][s], bfr, acc1,
                                                     0, 0, 0);
    }
#pragma unroll
    for (int r = 0; r < 4; ++r) {
      int f0 = lgrp * 4 + r;
      fires[f0 * 256 + rrow * 16 + lrow] = (acc0[r] >= 15.f);
      int f1 = 16 + lgrp * 4 + r;
      if (f1 < 30) fires[f1 * 256 + rrow * 16 + lrow] = (acc1[r] >= 15.f);
    }
  }
  __syncthreads();

  // 2x2 OR pool -> pooled[pos][c] (c 30/31 = 0)
  for (int idx = tid; idx < 2048; idx += 256) {
    int f = idx >> 6, pp = idx & 63;
    int py = pp >> 3, px = pp & 7;
    u16 v = 0;
    if (f < 30) {
      const u8* fb = &fires[f * 256 + py * 32 + px * 2];
      v = (fb[0] | fb[1] | fb[16] | fb[17]) ? (u16)0x3F80 : (u16)0;
    }
    pooled[pp * 32 + f] = v;
  }
  __syncthreads();

  // channels-last write: spk_cl[t][1+ty0/2+py][1+tx0/2+px][32]
  int pos = tid >> 2, part = tid & 3;
  int yy = 1 + (ty0 >> 1) + (pos >> 3), xx = 1 + (tx0 >> 1) + (pos & 7);
  *(short8*)(spk_cl + (((size_t)t * 82 + yy) * 82 + xx) * 32 + part * 8) =
      *(short8*)&pooled[pos * 32 + part * 8];
}

// ---------------------------------------------------------------------------
// K2: conv2 MFMA, direct-global channels-last fragments. grid 15*100,
// block 256 (4 waves). Tile: 256 f x 64 pos (16x x 4y); 9 K-steps (ky,kx),
// K=32=c; hi+lo weights. LDS only for the cross-wave f-reduction.
__global__ __launch_bounds__(256) void conv2_kernel(
    const u16* __restrict__ spk_cl, const u16* __restrict__ Whi,
    const u16* __restrict__ Wlo, float* __restrict__ maxv_ws,
    int* __restrict__ argm_ws) {
  __shared__ float redv[64 * 5];
  __shared__ int redi[64 * 5];

  int tid = threadIdx.x, b = blockIdx.x;
  int t = b / 100, tile = b % 100;
  int x0 = (tile % 5) * 16, y0 = (tile / 5) * 4;
  int lane = tid & 63, wave = tid >> 6, lrow = lane & 15, lgrp = lane >> 4;
  int fbase = wave * 64;

  f32x4 acc[4][4];
#pragma unroll
  for (int i = 0; i < 4; ++i)
#pragma unroll
    for (int j = 0; j < 4; ++j) acc[i][j] = (f32x4){0.f, 0.f, 0.f, 0.f};

  const u16* sb = spk_cl + (size_t)t * 82 * 82 * 32;

#pragma unroll
  for (int ks = 0; ks < 9; ++ks) {
    int ky = ks / 3, kx = ks % 3;
    short8 ahi[4], alo[4];
#pragma unroll
    for (int ft = 0; ft < 4; ++ft) {
      int f = fbase + ft * 16 + lrow;
      ahi[ft] = *(const short8*)(Whi + f * 288 + ks * 32 + lgrp * 8);
      alo[ft] = *(const short8*)(Wlo + f * 288 + ks * 32 + lgrp * 8);
    }
    short8 bfr[4];
#pragma unroll
    for (int pt = 0; pt < 4; ++pt)
      bfr[pt] = *(const short8*)(
          sb + (((y0 + pt + ky) * 82) + x0 + lrow + kx) * 32 + lgrp * 8);
#pragma unroll
    for (int ft = 0; ft < 4; ++ft)
#pragma unroll
      for (int pt = 0; pt < 4; ++pt) {
        acc[ft][pt] = __builtin_amdgcn_mfma_f32_16x16x32_bf16(
            ahi[ft], bfr[pt], acc[ft][pt], 0, 0, 0);
        acc[ft][pt] = __builtin_amdgcn_mfma_f32_16x16x32_bf16(
            alo[ft], bfr[pt], acc[ft][pt], 0, 0, 0);
      }
  }

  // epilogue: threshold >=10, per-pos max/argmax over f (first-max)
#pragma unroll
  for (int pt = 0; pt < 4; ++pt) {
    float bv = -1.f; int bf = 0;
#pragma unroll
    for (int ft = 0; ft < 4; ++ft)
#pragma unroll
      for (int r = 0; r < 4; ++r) {
        float v = acc[ft][pt][r];
        v = (v >= 10.f) ? v : 0.f;
        int f = fbase + ft * 16 + lgrp * 4 + r;
        if (v > bv) { bv = v; bf = f; }
      }
    {
      float ov = __shfl_xor(bv, 16); int of = __shfl_xor(bf, 16);
      if (ov > bv || (ov == bv && of < bf)) { bv = ov; bf = of; }
      ov = __shfl_xor(bv, 32); of = __shfl_xor(bf, 32);
      if (ov > bv || (ov == bv && of < bf)) { bv = ov; bf = of; }
    }
    if (lgrp == 0) {
      int p = pt * 16 + lrow;
      redv[p * 5 + wave] = bv;
      redi[p * 5 + wave] = bf;
    }
  }
  __syncthreads();
  if (tid < 64) {
    float bv = -1.f; int bf = 0x7fffffff;
#pragma unroll
    for (int w = 0; w < 4; ++w) {   // wave ascending = f ascending
      float v = redv[tid * 5 + w]; int f = redi[tid * 5 + w];
      if (v > bv || (v == bv && f < bf)) { bv = v; bf = f; }
    }
    int y = y0 + (tid >> 4), x = x0 + (tid & 15);
    int pos = y * 80 + x;
    maxv_ws[t * 6400 + pos] = bv;
    argm_ws[t * 6400 + pos] = bf;
  }
}

// ---------------------------------------------------------------------------
// K3: winmap + exact fp32 recompute. grid 75 = 25 pos-tiles x 3 t-groups(5).
// Per thread: one pos, 5 t; w2 value hoisted across the t-loop (15x fewer
// scattered w2 reads); channels-last activation reads are L1-hot.
__global__ __launch_bounds__(256) void recompute_kernel(
    const u16* __restrict__ spk_cl, const float* __restrict__ w2,
    const float* __restrict__ maxv, const int* __restrict__ argm,
    int* __restrict__ winmap, float* __restrict__ potwin) {
  int tid = threadIdx.x, b = blockIdx.x;
  int tile = b % 25, tg = b / 25;
  int t0 = tg * 5;
  int ty0 = (tile / 5) * 16, tx0 = (tile % 5) * 16;
  int py = tid >> 4, px = tid & 15;
  int h = ty0 + py, w = tx0 + px, pos = h * 80 + w;

  int nc = 0;
#pragma unroll
  for (int tt = 0; tt < T_STEPS; ++tt)
    nc += (maxv[tt * 6400 + pos] > 0.f) ? 1 : 0;
  int e = T_STEPS - nc; if (e > 14) e = 14;
  int win = argm[e * 6400 + pos];
  if (!(maxv[14 * 6400 + pos] > 0.f)) win = -1;
  if (tg == 0) winmap[pos] = win;

  float a0 = 0.f, a1 = 0.f, a2 = 0.f, a3 = 0.f, a4 = 0.f;
  if (win >= 0) {
    const float* wt = w2 + win * 270;
    const u16* sb = spk_cl + (size_t)t0 * 215168;   // 82*82*32
    for (int c = 0; c < 30; ++c) {   // exact fp32 chain (c, ky, kx) per t
#pragma unroll
      for (int kk = 0; kk < 9; ++kk) {
        int ky = kk / 3, kx = kk % 3;
        float wv = wt[c * 9 + kk];
        size_t base = (((size_t)(h + ky) * 82) + (w + kx)) * 32 + c;
        a0 = fmaf(wv, bf2f(sb[base]), a0);
        a1 = fmaf(wv, bf2f(sb[215168 + base]), a1);
        a2 = fmaf(wv, bf2f(sb[2 * 215168 + base]), a2);
        a3 = fmaf(wv, bf2f(sb[3 * 215168 + base]), a3);
        a4 = fmaf(wv, bf2f(sb[4 * 215168 + base]), a4);
      }
    }
  }
  potwin[(t0 + 0) * 6400 + pos] = (a0 >= 10.f) ? a0 : 0.f;
  potwin[(t0 + 1) * 6400 + pos] = (a1 >= 10.f) ? a1 : 0.f;
  potwin[(t0 + 2) * 6400 + pos] = (a2 >= 10.f) ? a2 : 0.f;
  potwin[(t0 + 3) * 6400 + pos] = (a3 >= 10.f) ? a3 : 0.f;
  potwin[(t0 + 4) * 6400 + pos] = (a4 >= 10.f) ? a4 : 0.f;
}

// ---------------------------------------------------------------------------
// K4: block 0 = get_k_winners; blocks 1-25 = sparse scatter into zeroed d_out
__global__ __launch_bounds__(1024) void finalize_kernel(
    const int* __restrict__ winmap, const float* __restrict__ potwin,
    float* __restrict__ out, float* __restrict__ out_win) {
  __shared__ float tv[6400];
  __shared__ int   tf[6400];
  __shared__ float wv_s[16];
  __shared__ int   wk_s[16];
  __shared__ int   sh_w[4];
  __shared__ float vmax_s;

  int tid = threadIdx.x;
  int b = blockIdx.x;

  if (b > 0) {
    int pos = (b - 1) * 256 + (tid & 255);
    int tq = tid >> 8;
    int win = winmap[pos];
    if (win < 0) return;
    int tend = tq * 4 + 4; if (tend > T_STEPS) tend = T_STEPS;
    for (int t = tq * 4; t < tend; ++t) {
      float p = potwin[t * 6400 + pos];
      int o = (t * 250 + win) * 6400 + pos;
      out[o] = (p > 0.f) ? 1.f : 0.f;
      out[24000000 + o] = p;
    }
    return;
  }

  int lane = tid & 63, wid = tid >> 6;

  float localmax = 0.f;
  for (int pos = tid; pos < 6400; pos += 1024) {
    int win = winmap[pos];
    float val = 0.f; int nspk = 0;
    if (win >= 0) {
#pragma unroll
      for (int t = 0; t < T_STEPS; ++t)
        nspk += (potwin[t * 6400 + pos] > 0.f) ? 1 : 0;
      int first = T_STEPS - nspk; if (first > 14) first = 14;
      val = potwin[first * 6400 + pos];
      if (nspk > 0 && val > localmax) localmax = val;
    }
    tv[pos] = val;
    tf[pos] = ((win + 1) << 4) | nspk;
  }
#pragma unroll
  for (int m = 1; m < 64; m <<= 1)
    localmax = fmaxf(localmax, __shfl_xor(localmax, m));
  if (lane == 0) wv_s[wid] = localmax;
  __syncthreads();
  if (tid == 0) {
    float m = 0.f;
#pragma unroll
    for (int w = 0; w < 16; ++w) m = fmaxf(m, wv_s[w]);
    vmax_s = m * (float)T_STEPS;
  }
  __syncthreads();
  float v = vmax_s;

  for (int pos = tid; pos < 6400; pos += 1024) {
    int meta = tf[pos];
    int win = (meta >> 4) - 1, nspk = meta & 15;
    tf[pos] = win;
    tv[pos] = (win >= 0) ? (float)nspk * (tv[pos] + v) : 0.f;
  }
  __syncthreads();

  for (int it = 0; it < 8; ++it) {
    float bv = -1.f; int bk = 0x7fffffff;
    for (int pos = tid; pos < 6400; pos += 1024) {
      float tvv = tv[pos];
      int key = tf[pos] * 6400 + pos;
      if (tvv > bv || (tvv == bv && key < bk)) { bv = tvv; bk = key; }
    }
#pragma unroll
    for (int m = 1; m < 64; m <<= 1) {
      float ov = __shfl_xor(bv, m); int ok = __shfl_xor(bk, m);
      if (ov > bv || (ov == bv && ok < bk)) { bv = ov; bk = ok; }
    }
    if (lane == 0) { wv_s[wid] = bv; wk_s[wid] = bk; }
    __syncthreads();
    if (tid == 0) {
      float mbv = -1.f; int mbk = 0x7fffffff;
#pragma unroll
      for (int w = 0; w < 16; ++w) {
        float ov = wv_s[w]; int ok = wk_s[w];
        if (ov > mbv || (ov == mbv && ok < mbk)) { mbv = ov; mbk = ok; }
      }
      int f = -1, r = -1, c = -1, valid = 0;
      if (mbv != 0.f) {
        f = mbk / 6400; int pos = mbk % 6400;
        r = pos / 80; c = pos % 80;
        valid = 1;
      }
      out_win[it * 3 + 0] = (float)f;
      out_win[it * 3 + 1] = (float)r;
      out_win[it * 3 + 2] = (float)c;
      sh_w[0] = f; sh_w[1] = r; sh_w[2] = c; sh_w[3] = valid;
    }
    __syncthreads();
    if (sh_w[3]) {
      int wf = sh_w[0], wr = sh_w[1], wc = sh_w[2];
      for (int pos = tid; pos < 6400; pos += 1024) {
        int r = pos / 80, c = pos % 80;
        int dr = r - wr; if (dr < 0) dr = -dr;
        int dc = c - wc; if (dc < 0) dc = -dc;
        if (tf[pos] == wf || (dr <= 1 && dc <= 1)) tv[pos] = 0.f;
      }
    }
    __syncthreads();
  }
}

// ---------------------------------------------------------------------------
extern "C" void kernel_launch(void* const* d_in, const int* in_sizes, int n_in,
                              void* d_out, int out_size, void* d_ws,
                              size_t ws_size, hipStream_t stream) {
  const int*   xin = (const int*)d_in[0];
  const float* w1  = (const float*)d_in[1];
  const float* w2  = (const float*)d_in[2];
  float* out = (float*)d_out;
  char*  ws  = (char*)d_ws;

  u16*   inp_cl = (u16*)(ws + INPCL_OFF);
  u16*   spk_cl = (u16*)(ws + SPKCL_OFF);
  u16*   w1cl   = (u16*)(ws + W1CL_OFF);
  u16*   Whi    = (u16*)(ws + WHI_OFF);
  u16*   Wlo    = (u16*)(ws + WLO_OFF);
  float* maxv   = (float*)(ws + MAXV_OFF);
  int*   argm   = (int*)(ws + ARGM_OFF);
  int*   winmap = (int*)(ws + WINMAP_OFF);
  float* potwin = (float*)(ws + POTWIN_OFF);

  prep_kernel<<<K1A_GRID, 256, 0, stream>>>(xin, w1, w2, inp_cl, w1cl, Whi,
                                            Wlo, spk_cl);
  conv1_fill_kernel<<<K1B_GRID, 256, 0, stream>>>(inp_cl, w1cl, spk_cl,
                                                  (float4v*)d_out,
                                                  out_size / 4);
  conv2_kernel<<<1500, 256, 0, stream>>>(spk_cl, Whi, Wlo, maxv, argm);
  recompute_kernel<<<75, 256, 0, stream>>>(spk_cl, w2, maxv, argm, winmap,
                                           potwin);
  finalize_kernel<<<26, 1024, 0, stream>>>(winmap, potwin, out,
                                           out + 48000000);
}

// Round 9
// 207.394 us; speedup vs baseline: 14.1451x; 1.3684x over previous
//
#include <hip/hip_runtime.h>

// ---------------------------------------------------------------------------
// MozafariMNIST2018 SNN forward (training branch, max_layer==2) for MI355X.
//
//  Channels-last MFMA convs (no im2col) + proven LDS-staged exact recompute.
//   K1a: repack xin->inp_cl | w1cl | w2 hi/lo | spk_cl + spk_row borders
//   K1b: conv1-MFMA (direct-global B-frags; writes spk_cl AND spk_row)
//        || d_out zero-fill
//   K2 : conv2-MFMA (direct-global frags, unroll-1 K loop)  [x2 this round
//        for attribution — idempotent]
//   K3 : winmap + exact-fp32 recompute (R5 design: 375 blocks, LDS patch)
//   K4 : get_k_winners (block 0) || sparse scatter
//  All output values from exact fp32 recompute -> absmax 0.
// ---------------------------------------------------------------------------

typedef unsigned short u16;
typedef unsigned char u8;
typedef __attribute__((ext_vector_type(8))) short short8;
typedef __attribute__((ext_vector_type(4))) float f32x4;
typedef __attribute__((ext_vector_type(4))) float float4v;

#define T_STEPS 15

// ws byte offsets (all 16B aligned)
#define INPCL_OFF   0u          // 15*164*168*8 u16 = 6,612,480
#define SPKCL_OFF   6612480u    // 15*82*82*32 u16  = 6,455,040
#define SPKROW_OFF  13067520u   // 15*30*82*82 u16  = 6,051,600
#define W1CL_OFF    19119120u   // 10240 u16
#define WHI_OFF     19139600u   // 73728 u16
#define WLO_OFF     19287056u   // 73728 u16
#define MAXV_OFF    19434512u   // 96000 f32
#define ARGM_OFF    19818512u   // 96000 i32
#define WINMAP_OFF  20202512u   // 6400 i32
#define POTWIN_OFF  20228112u   // 96000 f32 -> end 20,612,112

// K1a block partition
#define NB_REPACK 1615
#define NB_W1     40
#define NB_W2     288
#define NB_BORD   76
#define NB_BROW   18
#define K1A_GRID  (NB_REPACK + NB_W1 + NB_W2 + NB_BORD + NB_BROW)

// K1b block partition
#define NB_CONV1  1500
#define NB_FILL   2048
#define K1B_GRID  (NB_CONV1 + NB_FILL)

static __device__ __forceinline__ u16 f2bf_rne(float f) {
  unsigned u = __float_as_uint(f);
  unsigned r = u + 0x7FFFu + ((u >> 16) & 1u);
  return (u16)(r >> 16);
}
static __device__ __forceinline__ float bf2f(u16 b) {
  return __uint_as_float(((unsigned)b) << 16);
}

// ---------------------------------------------------------------------------
// K1a: layout prep + border rings
__global__ __launch_bounds__(256) void prep_kernel(
    const int* __restrict__ xin, const float* __restrict__ w1,
    const float* __restrict__ w2, u16* __restrict__ inp_cl,
    u16* __restrict__ w1cl, u16* __restrict__ Whi, u16* __restrict__ Wlo,
    u16* __restrict__ spk_cl, u16* __restrict__ spk_row) {
  int tid = threadIdx.x, b = blockIdx.x;

  if (b < NB_REPACK) {
    // xin (15,6,160,160) int -> inp_cl[t][164][168][8] bf16 binary
    int g = b * 256 + tid;
    if (g < 413280) {
      int t = g / 27552, rem = g % 27552;
      int yy = rem / 168, xx = rem % 168;
      int y = yy - 2, x = xx - 2;
      short8 sv = {0, 0, 0, 0, 0, 0, 0, 0};
      if ((unsigned)y < 160u && (unsigned)x < 160u) {
        const int* xb = xin + ((size_t)t * 6 * 160 + y) * 160 + x;
#pragma unroll
        for (int c = 0; c < 6; ++c)
          sv[c] = xb[c * 25600] ? (short)0x3F80 : (short)0;
      }
      *(short8*)(inp_cl + (size_t)g * 8) = sv;
    }
  } else if (b < NB_REPACK + NB_W1) {
    // w1 (30,6,5,5) -> w1cl[f32][ky5][kxb2][dx4*c8]  (k = dx*8+c)
    int idx = (b - NB_REPACK) * 256 + tid;   // < 10240
    int f = idx / 320, r = idx % 320;
    int ky = r / 64, r2 = r % 64;
    int kxb = r2 >> 5, k = r2 & 31;
    int dx = k >> 3, c = k & 7;
    int kx = kxb * 4 + dx;
    u16 v = 0;
    if (f < 30 && c < 6 && kx < 5)
      v = f2bf_rne(w1[(f * 6 + c) * 25 + ky * 5 + kx]);
    w1cl[idx] = v;
  } else if (b < NB_REPACK + NB_W1 + NB_W2) {
    // w2 (250,30,3,3) -> Whi/Wlo[f256][kk9][c32] hi+lo bf16 split
    int g2 = (b - NB_REPACK - NB_W1) * 256 + tid;   // < 73728
    int f = g2 / 288, r = g2 % 288;
    int kk = r >> 5, c = r & 31;
    u16 h = 0, l = 0;
    if (f < 250 && c < 30) {
      float w = w2[f * 270 + c * 9 + kk];
      h = f2bf_rne(w);
      l = f2bf_rne(w - bf2f(h));
    }
    Whi[g2] = h;
    Wlo[g2] = l;
  } else if (b < NB_REPACK + NB_W1 + NB_W2 + NB_BORD) {
    // spk_cl border ring zeros (pad of 82x82), 32 c per pos
    int u = (b - NB_REPACK - NB_W1 - NB_W2) * 256 + tid;
    if (u < 19440) {
      int pid = u >> 2, part = u & 3;
      int t = pid / 324, i = pid % 324;
      int row, col;
      if (i < 82) { row = 0; col = i; }
      else if (i < 164) { row = 81; col = i - 82; }
      else if (i < 244) { row = 1 + (i - 164); col = 0; }
      else { row = 1 + (i - 244); col = 81; }
      short8 z = {0, 0, 0, 0, 0, 0, 0, 0};
      *(short8*)(spk_cl + (((size_t)t * 82 + row) * 82 + col) * 32 +
                 part * 8) = z;
    }
  } else {
    // spk_row border ring zeros: 450 (t,c) planes x 324 ring positions
    int u0 = (b - NB_REPACK - NB_W1 - NB_W2 - NB_BORD) * 256 + tid;
    for (int v = u0; v < 145800; v += NB_BROW * 256) {
      int tc = v / 324, i = v % 324;
      int row, col;
      if (i < 82) { row = 0; col = i; }
      else if (i < 164) { row = 81; col = i - 82; }
      else if (i < 244) { row = 1 + (i - 164); col = 0; }
      else { row = 1 + (i - 244); col = 81; }
      spk_row[(size_t)tc * 6724 + row * 82 + col] = 0;
    }
  }
}

// ---------------------------------------------------------------------------
// K1b: conv1 MFMA (direct-global channels-last B-frags) || d_out zero fill.
__global__ __launch_bounds__(256) void conv1_fill_kernel(
    const u16* __restrict__ inp_cl, const u16* __restrict__ w1cl,
    u16* __restrict__ spk_cl, u16* __restrict__ spk_row,
    float4v* __restrict__ out4, int out_n4) {
  __shared__ u8 fires[30 * 256];
  __shared__ u16 pooled[64 * 32];

  int tid = threadIdx.x, b = blockIdx.x;

  if (b >= NB_CONV1) {
    int i = (b - NB_CONV1) * 256 + tid;
    float4v z = {0.f, 0.f, 0.f, 0.f};
    for (; i < out_n4; i += NB_FILL * 256) out4[i] = z;
    return;
  }

  int t = b / 100, tile = b % 100;
  int ty0 = (tile / 10) * 16, tx0 = (tile % 10) * 16;
  int lane = tid & 63, wave = tid >> 6, lrow = lane & 15, lgrp = lane >> 4;

  short8 afr[2][10];
#pragma unroll
  for (int mt = 0; mt < 2; ++mt)
#pragma unroll
    for (int s = 0; s < 10; ++s)
      afr[mt][s] =
          *(const short8*)(w1cl + ((mt * 16 + lrow) * 10 + s) * 32 + lgrp * 8);

  const u16* ib = inp_cl + (size_t)t * 164 * 168 * 8;

  for (int ph = 0; ph < 4; ++ph) {
    int rrow = ph * 4 + wave;
    int oy = ty0 + rrow;
    f32x4 acc0 = {0.f, 0.f, 0.f, 0.f}, acc1 = {0.f, 0.f, 0.f, 0.f};
#pragma unroll
    for (int s = 0; s < 10; ++s) {
      int ky = s >> 1, kxb = s & 1;
      short8 bfr = *(const short8*)(
          ib + (((oy + ky) * 168) + tx0 + lrow + kxb * 4 + lgrp) * 8);
      acc0 = __builtin_amdgcn_mfma_f32_16x16x32_bf16(afr[0][s], bfr, acc0,
                                                     0, 0, 0);
      acc1 = __builtin_amdgcn_mfma_f32_16x16x32_bf16(afr[1][s], bfr, acc1,
                                                     0, 0, 0);
    }
#pragma unroll
    for (int r = 0; r < 4; ++r) {
      int f0 = lgrp * 4 + r;
      fires[f0 * 256 + rrow * 16 + lrow] = (acc0[r] >= 15.f);
      int f1 = 16 + lgrp * 4 + r;
      if (f1 < 30) fires[f1 * 256 + rrow * 16 + lrow] = (acc1[r] >= 15.f);
    }
  }
  __syncthreads();

  int pby0 = (ty0 >> 1) + 1, pbx0 = (tx0 >> 1) + 1;

  // 2x2 OR pool -> pooled[pos][c] (c 30/31 = 0) for channels-last write
  for (int idx = tid; idx < 2048; idx += 256) {
    int f = idx >> 6, pp = idx & 63;
    int py = pp >> 3, px = pp & 7;
    u16 v = 0;
    if (f < 30) {
      const u8* fb = &fires[f * 256 + py * 32 + px * 2];
      v = (fb[0] | fb[1] | fb[16] | fb[17]) ? (u16)0x3F80 : (u16)0;
    }
    pooled[pp * 32 + f] = v;
  }
  // row-major write directly from fires (conflict-free reads)
  for (int idx = tid; idx < 1920; idx += 256) {
    int f = idx >> 6, pp = idx & 63;
    int py = pp >> 3, px = pp & 7;
    const u8* fb = &fires[f * 256 + py * 32 + px * 2];
    u16 v = (fb[0] | fb[1] | fb[16] | fb[17]) ? (u16)0x3F80 : (u16)0;
    spk_row[((t * 30 + f) * 82 + pby0 + py) * 82 + pbx0 + px] = v;
  }
  __syncthreads();

  // channels-last write: spk_cl[t][pby0+py][pbx0+px][32]
  int pos = tid >> 2, part = tid & 3;
  int yy = pby0 + (pos >> 3), xx = pbx0 + (pos & 7);
  *(short8*)(spk_cl + (((size_t)t * 82 + yy) * 82 + xx) * 32 + part * 8) =
      *(short8*)&pooled[pos * 32 + part * 8];
}

// ---------------------------------------------------------------------------
// K2: conv2 MFMA, direct-global channels-last fragments. grid 15*100,
// block 256 (4 waves). Tile: 256 f x 64 pos (16x x 4y); 9 K-steps (ky,kx),
// K=32=c; hi+lo weights. Unroll-1 K loop (bounded VGPR; cross-wave hiding).
__global__ __launch_bounds__(256) void conv2_kernel(
    const u16* __restrict__ spk_cl, const u16* __restrict__ Whi,
    const u16* __restrict__ Wlo, float* __restrict__ maxv_ws,
    int* __restrict__ argm_ws) {
  __shared__ float redv[64 * 5];
  __shared__ int redi[64 * 5];

  int tid = threadIdx.x, b = blockIdx.x;
  int t = b / 100, tile = b % 100;
  int x0 = (tile % 5) * 16, y0 = (tile / 5) * 4;
  int lane = tid & 63, wave = tid >> 6, lrow = lane & 15, lgrp = lane >> 4;
  int fbase = wave * 64;

  f32x4 acc[4][4];
#pragma unroll
  for (int i = 0; i < 4; ++i)
#pragma unroll
    for (int j = 0; j < 4; ++j) acc[i][j] = (f32x4){0.f, 0.f, 0.f, 0.f};

  const u16* sb = spk_cl + (size_t)t * 82 * 82 * 32;
  const u16* whb = Whi + (size_t)(fbase + lrow) * 288 + lgrp * 8;
  const u16* wlb = Wlo + (size_t)(fbase + lrow) * 288 + lgrp * 8;

#pragma unroll 1
  for (int ks = 0; ks < 9; ++ks) {
    int ky = (ks >= 6) ? 2 : ((ks >= 3) ? 1 : 0);
    int kx = ks - ky * 3;
    short8 ahi[4], alo[4], bfr[4];
#pragma unroll
    for (int ft = 0; ft < 4; ++ft) {
      ahi[ft] = *(const short8*)(whb + (size_t)ft * 16 * 288 + ks * 32);
      alo[ft] = *(const short8*)(wlb + (size_t)ft * 16 * 288 + ks * 32);
    }
#pragma unroll
    for (int pt = 0; pt < 4; ++pt)
      bfr[pt] = *(const short8*)(
          sb + (((y0 + pt + ky) * 82) + x0 + lrow + kx) * 32 + lgrp * 8);
#pragma unroll
    for (int ft = 0; ft < 4; ++ft)
#pragma unroll
      for (int pt = 0; pt < 4; ++pt) {
        acc[ft][pt] = __builtin_amdgcn_mfma_f32_16x16x32_bf16(
            ahi[ft], bfr[pt], acc[ft][pt], 0, 0, 0);
        acc[ft][pt] = __builtin_amdgcn_mfma_f32_16x16x32_bf16(
            alo[ft], bfr[pt], acc[ft][pt], 0, 0, 0);
      }
  }

  // epilogue: threshold >=10, per-pos max/argmax over f (first-max)
#pragma unroll
  for (int pt = 0; pt < 4; ++pt) {
    float bv = -1.f; int bf = 0;
#pragma unroll
    for (int ft = 0; ft < 4; ++ft)
#pragma unroll
      for (int r = 0; r < 4; ++r) {
        float v = acc[ft][pt][r];
        v = (v >= 10.f) ? v : 0.f;
        int f = fbase + ft * 16 + lgrp * 4 + r;
        if (v > bv) { bv = v; bf = f; }
      }
    {
      float ov = __shfl_xor(bv, 16); int of = __shfl_xor(bf, 16);
      if (ov > bv || (ov == bv && of < bf)) { bv = ov; bf = of; }
      ov = __shfl_xor(bv, 32); of = __shfl_xor(bf, 32);
      if (ov > bv || (ov == bv && of < bf)) { bv = ov; bf = of; }
    }
    if (lgrp == 0) {
      int p = pt * 16 + lrow;
      redv[p * 5 + wave] = bv;
      redi[p * 5 + wave] = bf;
    }
  }
  __syncthreads();
  if (tid < 64) {
    float bv = -1.f; int bf = 0x7fffffff;
#pragma unroll
    for (int w = 0; w < 4; ++w) {   // wave ascending = f ascending
      float v = redv[tid * 5 + w]; int f = redi[tid * 5 + w];
      if (v > bv || (v == bv && f < bf)) { bv = v; bf = f; }
    }
    int y = y0 + (tid >> 4), x = x0 + (tid & 15);
    int pos = y * 80 + x;
    maxv_ws[t * 6400 + pos] = bv;
    argm_ws[t * 6400 + pos] = bf;
  }
}

// ---------------------------------------------------------------------------
// K3: winmap + exact fp32 recompute (R5 design). grid 15*25, block 256.
// LDS-staged row-major patch, coalesced; per-thread exact (c,ky,kx) chain.
__global__ __launch_bounds__(256) void recompute_kernel(
    const u16* __restrict__ spk_row, const float* __restrict__ w2,
    const float* __restrict__ maxv, const int* __restrict__ argm,
    int* __restrict__ winmap, float* __restrict__ potwin) {
  __shared__ u16 patch[30 * 18 * 18];

  int tid = threadIdx.x, b = blockIdx.x;
  int t = b / 25, tile = b % 25;
  int ty0 = (tile / 5) * 16, tx0 = (tile % 5) * 16;

  const u16* base = spk_row + (size_t)t * 30 * 6724;
  for (int idx = tid; idx < 9720; idx += 256) {
    int c = idx / 324, rem = idx % 324;
    int dy = rem / 18, dx = rem % 18;
    patch[idx] = base[c * 6724 + (ty0 + dy) * 82 + (tx0 + dx)];
  }

  int py = tid >> 4, px = tid & 15;
  int pos = (ty0 + py) * 80 + tx0 + px;

  int nc = 0;
#pragma unroll
  for (int tt = 0; tt < T_STEPS; ++tt)
    nc += (maxv[tt * 6400 + pos] > 0.f) ? 1 : 0;
  int e = T_STEPS - nc; if (e > 14) e = 14;
  int win = argm[e * 6400 + pos];
  if (!(maxv[14 * 6400 + pos] > 0.f)) win = -1;
  if (t == 0) winmap[pos] = win;

  __syncthreads();

  float p = 0.f;
  if (win >= 0) {
    const float* wt = w2 + win * 270;
    float a = 0.f;
    for (int c = 0; c < 30; ++c) {        // exact fp32 chain (matches ref)
#pragma unroll
      for (int ky = 0; ky < 3; ++ky)
#pragma unroll
        for (int kx = 0; kx < 3; ++kx)
          a = fmaf(wt[c * 9 + ky * 3 + kx],
                   bf2f(patch[c * 324 + (py + ky) * 18 + (px + kx)]), a);
    }
    p = (a >= 10.f) ? a : 0.f;
  }
  potwin[t * 6400 + pos] = p;
}

// ---------------------------------------------------------------------------
// K4: block 0 = get_k_winners; blocks 1-25 = sparse scatter into zeroed d_out
__global__ __launch_bounds__(1024) void finalize_kernel(
    const int* __restrict__ winmap, const float* __restrict__ potwin,
    float* __restrict__ out, float* __restrict__ out_win) {
  __shared__ float tv[6400];
  __shared__ int   tf[6400];
  __shared__ float wv_s[16];
  __shared__ int   wk_s[16];
  __shared__ int   sh_w[4];
  __shared__ float vmax_s;

  int tid = threadIdx.x;
  int b = blockIdx.x;

  if (b > 0) {
    int pos = (b - 1) * 256 + (tid & 255);
    int tq = tid >> 8;
    int win = winmap[pos];
    if (win < 0) return;
    int tend = tq * 4 + 4; if (tend > T_STEPS) tend = T_STEPS;
    for (int t = tq * 4; t < tend; ++t) {
      float p = potwin[t * 6400 + pos];
      int o = (t * 250 + win) * 6400 + pos;
      out[o] = (p > 0.f) ? 1.f : 0.f;
      out[24000000 + o] = p;
    }
    return;
  }

  int lane = tid & 63, wid = tid >> 6;

  float localmax = 0.f;
  for (int pos = tid; pos < 6400; pos += 1024) {
    int win = winmap[pos];
    float val = 0.f; int nspk = 0;
    if (win >= 0) {
#pragma unroll
      for (int t = 0; t < T_STEPS; ++t)
        nspk += (potwin[t * 6400 + pos] > 0.f) ? 1 : 0;
      int first = T_STEPS - nspk; if (first > 14) first = 14;
      val = potwin[first * 6400 + pos];
      if (nspk > 0 && val > localmax) localmax = val;
    }
    tv[pos] = val;
    tf[pos] = ((win + 1) << 4) | nspk;
  }
#pragma unroll
  for (int m = 1; m < 64; m <<= 1)
    localmax = fmaxf(localmax, __shfl_xor(localmax, m));
  if (lane == 0) wv_s[wid] = localmax;
  __syncthreads();
  if (tid == 0) {
    float m = 0.f;
#pragma unroll
    for (int w = 0; w < 16; ++w) m = fmaxf(m, wv_s[w]);
    vmax_s = m * (float)T_STEPS;
  }
  __syncthreads();
  float v = vmax_s;

  for (int pos = tid; pos < 6400; pos += 1024) {
    int meta = tf[pos];
    int win = (meta >> 4) - 1, nspk = meta & 15;
    tf[pos] = win;
    tv[pos] = (win >= 0) ? (float)nspk * (tv[pos] + v) : 0.f;
  }
  __syncthreads();

  for (int it = 0; it < 8; ++it) {
    float bv = -1.f; int bk = 0x7fffffff;
    for (int pos = tid; pos < 6400; pos += 1024) {
      float tvv = tv[pos];
      int key = tf[pos] * 6400 + pos;
      if (tvv > bv || (tvv == bv && key < bk)) { bv = tvv; bk = key; }
    }
#pragma unroll
    for (int m = 1; m < 64; m <<= 1) {
      float ov = __shfl_xor(bv, m); int ok = __shfl_xor(bk, m);
      if (ov > bv || (ov == bv && ok < bk)) { bv = ov; bk = ok; }
    }
    if (lane == 0) { wv_s[wid] = bv; wk_s[wid] = bk; }
    __syncthreads();
    if (tid == 0) {
      float mbv = -1.f; int mbk = 0x7fffffff;
#pragma unroll
      for (int w = 0; w < 16; ++w) {
        float ov = wv_s[w]; int ok = wk_s[w];
        if (ov > mbv || (ov == mbv && ok < mbk)) { mbv = ov; mbk = ok; }
      }
      int f = -1, r = -1, c = -1, valid = 0;
      if (mbv != 0.f) {
        f = mbk / 6400; int pos = mbk % 6400;
        r = pos / 80; c = pos % 80;
        valid = 1;
      }
      out_win[it * 3 + 0] = (float)f;
      out_win[it * 3 + 1] = (float)r;
      out_win[it * 3 + 2] = (float)c;
      sh_w[0] = f; sh_w[1] = r; sh_w[2] = c; sh_w[3] = valid;
    }
    __syncthreads();
    if (sh_w[3]) {
      int wf = sh_w[0], wr = sh_w[1], wc = sh_w[2];
      for (int pos = tid; pos < 6400; pos += 1024) {
        int r = pos / 80, c = pos % 80;
        int dr = r - wr; if (dr < 0) dr = -dr;
        int dc = c - wc; if (dc < 0) dc = -dc;
        if (tf[pos] == wf || (dr <= 1 && dc <= 1)) tv[pos] = 0.f;
      }
    }
    __syncthreads();
  }
}

// ---------------------------------------------------------------------------
extern "C" void kernel_launch(void* const* d_in, const int* in_sizes, int n_in,
                              void* d_out, int out_size, void* d_ws,
                              size_t ws_size, hipStream_t stream) {
  const int*   xin = (const int*)d_in[0];
  const float* w1  = (const float*)d_in[1];
  const float* w2  = (const float*)d_in[2];
  float* out = (float*)d_out;
  char*  ws  = (char*)d_ws;

  u16*   inp_cl  = (u16*)(ws + INPCL_OFF);
  u16*   spk_cl  = (u16*)(ws + SPKCL_OFF);
  u16*   spk_row = (u16*)(ws + SPKROW_OFF);
  u16*   w1cl    = (u16*)(ws + W1CL_OFF);
  u16*   Whi     = (u16*)(ws + WHI_OFF);
  u16*   Wlo     = (u16*)(ws + WLO_OFF);
  float* maxv    = (float*)(ws + MAXV_OFF);
  int*   argm    = (int*)(ws + ARGM_OFF);
  int*   winmap  = (int*)(ws + WINMAP_OFF);
  float* potwin  = (float*)(ws + POTWIN_OFF);

  prep_kernel<<<K1A_GRID, 256, 0, stream>>>(xin, w1, w2, inp_cl, w1cl, Whi,
                                            Wlo, spk_cl, spk_row);
  conv1_fill_kernel<<<K1B_GRID, 256, 0, stream>>>(inp_cl, w1cl, spk_cl,
                                                  spk_row, (float4v*)d_out,
                                                  out_size / 4);
  // conv2 launched TWICE (idempotent) for attribution: dur = rest + 2*conv2
  conv2_kernel<<<1500, 256, 0, stream>>>(spk_cl, Whi, Wlo, maxv, argm);
  conv2_kernel<<<1500, 256, 0, stream>>>(spk_cl, Whi, Wlo, maxv, argm);
  recompute_kernel<<<375, 256, 0, stream>>>(spk_row, w2, maxv, argm, winmap,
                                            potwin);
  finalize_kernel<<<26, 1024, 0, stream>>>(winmap, potwin, out,
                                           out + 48000000);
}

// Round 10
// 151.979 us; speedup vs baseline: 19.3027x; 1.3646x over previous
//
#include <hip/hip_runtime.h>

// ---------------------------------------------------------------------------
// MozafariMNIST2018 SNN forward (training branch, max_layer==2) for MI355X.
//
//  Channels-last MFMA convs (no im2col) + LDS-staged exact recompute.
//   K1a: repack xin->inp_cl | w1cl | w2 hi/lo [ks][f][c] | border rings
//   K1b: conv1-MFMA (direct-global B-frags; writes spk_cl AND spk_row)
//        || d_out zero-fill
//   K2 : conv2-MFMA 512thr/8wave, [ks][f][c] coalesced weights, 1-step
//        register double-buffer (latency hiding: ~4 waves/SIMD resident)
//   K3 : winmap + exact-fp32 recompute (u32-vectorized LDS staging)
//   K4 : get_k_winners (block 0) || sparse scatter
//  All output values from exact fp32 recompute -> absmax 0.
// ---------------------------------------------------------------------------

typedef unsigned short u16;
typedef unsigned char u8;
typedef __attribute__((ext_vector_type(8))) short short8;
typedef __attribute__((ext_vector_type(4))) float f32x4;
typedef __attribute__((ext_vector_type(4))) float float4v;

#define T_STEPS 15

// ws byte offsets (all 16B aligned)
#define INPCL_OFF   0u          // 15*164*168*8 u16 = 6,612,480
#define SPKCL_OFF   6612480u    // 15*82*82*32 u16  = 6,455,040
#define SPKROW_OFF  13067520u   // 15*30*82*82 u16  = 6,051,600
#define W1CL_OFF    19119120u   // 10240 u16
#define WHI_OFF     19139600u   // 73728 u16 ([ks9][f256][c32])
#define WLO_OFF     19287056u   // 73728 u16
#define MAXV_OFF    19434512u   // 96000 f32
#define ARGM_OFF    19818512u   // 96000 i32
#define WINMAP_OFF  20202512u   // 6400 i32
#define POTWIN_OFF  20228112u   // 96000 f32 -> end 20,612,112

// K1a block partition
#define NB_REPACK 1615
#define NB_W1     40
#define NB_W2     288
#define NB_BORD   76
#define NB_BROW   18
#define K1A_GRID  (NB_REPACK + NB_W1 + NB_W2 + NB_BORD + NB_BROW)

// K1b block partition
#define NB_CONV1  1500
#define NB_FILL   2048
#define K1B_GRID  (NB_CONV1 + NB_FILL)

static __device__ __forceinline__ u16 f2bf_rne(float f) {
  unsigned u = __float_as_uint(f);
  unsigned r = u + 0x7FFFu + ((u >> 16) & 1u);
  return (u16)(r >> 16);
}
static __device__ __forceinline__ float bf2f(u16 b) {
  return __uint_as_float(((unsigned)b) << 16);
}

// ---------------------------------------------------------------------------
// K1a: layout prep + border rings
__global__ __launch_bounds__(256) void prep_kernel(
    const int* __restrict__ xin, const float* __restrict__ w1,
    const float* __restrict__ w2, u16* __restrict__ inp_cl,
    u16* __restrict__ w1cl, u16* __restrict__ Whi, u16* __restrict__ Wlo,
    u16* __restrict__ spk_cl, u16* __restrict__ spk_row) {
  int tid = threadIdx.x, b = blockIdx.x;

  if (b < NB_REPACK) {
    // xin (15,6,160,160) int -> inp_cl[t][164][168][8] bf16 binary
    int g = b * 256 + tid;
    if (g < 413280) {
      int t = g / 27552, rem = g % 27552;
      int yy = rem / 168, xx = rem % 168;
      int y = yy - 2, x = xx - 2;
      short8 sv = {0, 0, 0, 0, 0, 0, 0, 0};
      if ((unsigned)y < 160u && (unsigned)x < 160u) {
        const int* xb = xin + ((size_t)t * 6 * 160 + y) * 160 + x;
#pragma unroll
        for (int c = 0; c < 6; ++c)
          sv[c] = xb[c * 25600] ? (short)0x3F80 : (short)0;
      }
      *(short8*)(inp_cl + (size_t)g * 8) = sv;
    }
  } else if (b < NB_REPACK + NB_W1) {
    // w1 (30,6,5,5) -> w1cl[f32][ky5][kxb2][dx4*c8]  (k = dx*8+c)
    int idx = (b - NB_REPACK) * 256 + tid;   // < 10240
    int f = idx / 320, r = idx % 320;
    int ky = r / 64, r2 = r % 64;
    int kxb = r2 >> 5, k = r2 & 31;
    int dx = k >> 3, c = k & 7;
    int kx = kxb * 4 + dx;
    u16 v = 0;
    if (f < 30 && c < 6 && kx < 5)
      v = f2bf_rne(w1[(f * 6 + c) * 25 + ky * 5 + kx]);
    w1cl[idx] = v;
  } else if (b < NB_REPACK + NB_W1 + NB_W2) {
    // w2 (250,30,3,3) -> Whi/Wlo[ks9][f256][c32] hi+lo bf16 split
    int g2 = (b - NB_REPACK - NB_W1) * 256 + tid;   // < 73728
    int ks = g2 / 8192, r = g2 % 8192;
    int f = r >> 5, c = r & 31;
    u16 h = 0, l = 0;
    if (f < 250 && c < 30) {
      float w = w2[f * 270 + c * 9 + ks];
      h = f2bf_rne(w);
      l = f2bf_rne(w - bf2f(h));
    }
    Whi[g2] = h;
    Wlo[g2] = l;
  } else if (b < NB_REPACK + NB_W1 + NB_W2 + NB_BORD) {
    // spk_cl border ring zeros (pad of 82x82), 32 c per pos
    int u = (b - NB_REPACK - NB_W1 - NB_W2) * 256 + tid;
    if (u < 19440) {
      int pid = u >> 2, part = u & 3;
      int t = pid / 324, i = pid % 324;
      int row, col;
      if (i < 82) { row = 0; col = i; }
      else if (i < 164) { row = 81; col = i - 82; }
      else if (i < 244) { row = 1 + (i - 164); col = 0; }
      else { row = 1 + (i - 244); col = 81; }
      short8 z = {0, 0, 0, 0, 0, 0, 0, 0};
      *(short8*)(spk_cl + (((size_t)t * 82 + row) * 82 + col) * 32 +
                 part * 8) = z;
    }
  } else {
    // spk_row border ring zeros: 450 (t,c) planes x 324 ring positions
    int u0 = (b - NB_REPACK - NB_W1 - NB_W2 - NB_BORD) * 256 + tid;
    for (int v = u0; v < 145800; v += NB_BROW * 256) {
      int tc = v / 324, i = v % 324;
      int row, col;
      if (i < 82) { row = 0; col = i; }
      else if (i < 164) { row = 81; col = i - 82; }
      else if (i < 244) { row = 1 + (i - 164); col = 0; }
      else { row = 1 + (i - 244); col = 81; }
      spk_row[(size_t)tc * 6724 + row * 82 + col] = 0;
    }
  }
}

// ---------------------------------------------------------------------------
// K1b: conv1 MFMA (direct-global channels-last B-frags) || d_out zero fill.
__global__ __launch_bounds__(256) void conv1_fill_kernel(
    const u16* __restrict__ inp_cl, const u16* __restrict__ w1cl,
    u16* __restrict__ spk_cl, u16* __restrict__ spk_row,
    float4v* __restrict__ out4, int out_n4) {
  __shared__ u8 fires[30 * 256];
  __shared__ u16 pooled[64 * 32];

  int tid = threadIdx.x, b = blockIdx.x;

  if (b >= NB_CONV1) {
    int i = (b - NB_CONV1) * 256 + tid;
    float4v z = {0.f, 0.f, 0.f, 0.f};
    for (; i < out_n4; i += NB_FILL * 256) out4[i] = z;
    return;
  }

  int t = b / 100, tile = b % 100;
  int ty0 = (tile / 10) * 16, tx0 = (tile % 10) * 16;
  int lane = tid & 63, wave = tid >> 6, lrow = lane & 15, lgrp = lane >> 4;

  short8 afr[2][10];
#pragma unroll
  for (int mt = 0; mt < 2; ++mt)
#pragma unroll
    for (int s = 0; s < 10; ++s)
      afr[mt][s] =
          *(const short8*)(w1cl + ((mt * 16 + lrow) * 10 + s) * 32 + lgrp * 8);

  const u16* ib = inp_cl + (size_t)t * 164 * 168 * 8;

  for (int ph = 0; ph < 4; ++ph) {
    int rrow = ph * 4 + wave;
    int oy = ty0 + rrow;
    f32x4 acc0 = {0.f, 0.f, 0.f, 0.f}, acc1 = {0.f, 0.f, 0.f, 0.f};
#pragma unroll
    for (int s = 0; s < 10; ++s) {
      int ky = s >> 1, kxb = s & 1;
      short8 bfr = *(const short8*)(
          ib + (((oy + ky) * 168) + tx0 + lrow + kxb * 4 + lgrp) * 8);
      acc0 = __builtin_amdgcn_mfma_f32_16x16x32_bf16(afr[0][s], bfr, acc0,
                                                     0, 0, 0);
      acc1 = __builtin_amdgcn_mfma_f32_16x16x32_bf16(afr[1][s], bfr, acc1,
                                                     0, 0, 0);
    }
#pragma unroll
    for (int r = 0; r < 4; ++r) {
      int f0 = lgrp * 4 + r;
      fires[f0 * 256 + rrow * 16 + lrow] = (acc0[r] >= 15.f);
      int f1 = 16 + lgrp * 4 + r;
      if (f1 < 30) fires[f1 * 256 + rrow * 16 + lrow] = (acc1[r] >= 15.f);
    }
  }
  __syncthreads();

  int pby0 = (ty0 >> 1) + 1, pbx0 = (tx0 >> 1) + 1;

  for (int idx = tid; idx < 2048; idx += 256) {
    int f = idx >> 6, pp = idx & 63;
    int py = pp >> 3, px = pp & 7;
    u16 v = 0;
    if (f < 30) {
      const u8* fb = &fires[f * 256 + py * 32 + px * 2];
      v = (fb[0] | fb[1] | fb[16] | fb[17]) ? (u16)0x3F80 : (u16)0;
    }
    pooled[pp * 32 + f] = v;
  }
  for (int idx = tid; idx < 1920; idx += 256) {
    int f = idx >> 6, pp = idx & 63;
    int py = pp >> 3, px = pp & 7;
    const u8* fb = &fires[f * 256 + py * 32 + px * 2];
    u16 v = (fb[0] | fb[1] | fb[16] | fb[17]) ? (u16)0x3F80 : (u16)0;
    spk_row[((t * 30 + f) * 82 + pby0 + py) * 82 + pbx0 + px] = v;
  }
  __syncthreads();

  int pos = tid >> 2, part = tid & 3;
  int yy = pby0 + (pos >> 3), xx = pbx0 + (pos & 7);
  *(short8*)(spk_cl + (((size_t)t * 82 + yy) * 82 + xx) * 32 + part * 8) =
      *(short8*)&pooled[pos * 32 + part * 8];
}

// ---------------------------------------------------------------------------
// K2: conv2 MFMA. grid 1500, block 512 (8 waves x 32 f). 64 pos (16x x 4y).
// Weights [ks][f][c]: each weight-load instruction = 1KB contiguous.
// 1-step register double-buffer: ks+1 loads issued before ks MFMAs.
__global__ __launch_bounds__(512) void conv2_kernel(
    const u16* __restrict__ spk_cl, const u16* __restrict__ Whi,
    const u16* __restrict__ Wlo, float* __restrict__ maxv_ws,
    int* __restrict__ argm_ws) {
  __shared__ float redv[64 * 9];
  __shared__ int redi[64 * 9];

  int tid = threadIdx.x, b = blockIdx.x;
  int t = b / 100, tile = b % 100;
  int x0 = (tile % 5) * 16, y0 = (tile / 5) * 4;
  int lane = tid & 63, wave = tid >> 6, lrow = lane & 15, lgrp = lane >> 4;
  int fbase = wave * 32;

  f32x4 acc[2][4];
#pragma unroll
  for (int i = 0; i < 2; ++i)
#pragma unroll
    for (int j = 0; j < 4; ++j) acc[i][j] = (f32x4){0.f, 0.f, 0.f, 0.f};

  const u16* sb = spk_cl + (size_t)t * 82 * 82 * 32;
  const u16* whb = Whi + (fbase + lrow) * 32 + lgrp * 8;
  const u16* wlb = Wlo + (fbase + lrow) * 32 + lgrp * 8;

  short8 ah[2][2], al[2][2], bfv[2][4];   // [ks&1][...] -> static under unroll
#pragma unroll
  for (int ft = 0; ft < 2; ++ft) {
    ah[0][ft] = *(const short8*)(whb + ft * 512);
    al[0][ft] = *(const short8*)(wlb + ft * 512);
  }
#pragma unroll
  for (int pt = 0; pt < 4; ++pt)
    bfv[0][pt] =
        *(const short8*)(sb + (((y0 + pt) * 82) + x0 + lrow) * 32 + lgrp * 8);

#pragma unroll
  for (int ks = 0; ks < 9; ++ks) {
    int cur = ks & 1, nxt = cur ^ 1;
    if (ks < 8) {
      int kn = ks + 1;
      int kyn = kn / 3, kxn = kn % 3;
#pragma unroll
      for (int ft = 0; ft < 2; ++ft) {
        ah[nxt][ft] = *(const short8*)(whb + kn * 8192 + ft * 512);
        al[nxt][ft] = *(const short8*)(wlb + kn * 8192 + ft * 512);
      }
#pragma unroll
      for (int pt = 0; pt < 4; ++pt)
        bfv[nxt][pt] = *(const short8*)(
            sb + (((y0 + pt + kyn) * 82) + x0 + lrow + kxn) * 32 + lgrp * 8);
    }
#pragma unroll
    for (int ft = 0; ft < 2; ++ft)
#pragma unroll
      for (int pt = 0; pt < 4; ++pt) {
        acc[ft][pt] = __builtin_amdgcn_mfma_f32_16x16x32_bf16(
            ah[cur][ft], bfv[cur][pt], acc[ft][pt], 0, 0, 0);
        acc[ft][pt] = __builtin_amdgcn_mfma_f32_16x16x32_bf16(
            al[cur][ft], bfv[cur][pt], acc[ft][pt], 0, 0, 0);
      }
  }

  // epilogue: threshold >=10, per-pos max/argmax over f (first-max)
#pragma unroll
  for (int pt = 0; pt < 4; ++pt) {
    float bv = -1.f; int bf = 0;
#pragma unroll
    for (int ft = 0; ft < 2; ++ft)
#pragma unroll
      for (int r = 0; r < 4; ++r) {
        float v = acc[ft][pt][r];
        v = (v >= 10.f) ? v : 0.f;
        int f = fbase + ft * 16 + lgrp * 4 + r;
        if (v > bv) { bv = v; bf = f; }
      }
    {
      float ov = __shfl_xor(bv, 16); int of = __shfl_xor(bf, 16);
      if (ov > bv || (ov == bv && of < bf)) { bv = ov; bf = of; }
      ov = __shfl_xor(bv, 32); of = __shfl_xor(bf, 32);
      if (ov > bv || (ov == bv && of < bf)) { bv = ov; bf = of; }
    }
    if (lgrp == 0) {
      int p = pt * 16 + lrow;
      redv[p * 9 + wave] = bv;
      redi[p * 9 + wave] = bf;
    }
  }
  __syncthreads();
  if (tid < 64) {
    float bv = -1.f; int bf = 0x7fffffff;
#pragma unroll
    for (int w = 0; w < 8; ++w) {   // wave ascending = f ascending
      float v = redv[tid * 9 + w]; int f = redi[tid * 9 + w];
      if (v > bv || (v == bv && f < bf)) { bv = v; bf = f; }
    }
    int y = y0 + (tid >> 4), x = x0 + (tid & 15);
    int pos = y * 80 + x;
    maxv_ws[t * 6400 + pos] = bv;
    argm_ws[t * 6400 + pos] = bf;
  }
}

// ---------------------------------------------------------------------------
// K3: winmap + exact fp32 recompute. grid 15*25, block 256.
// u32-vectorized LDS staging; per-thread exact (c,ky,kx) fp32 chain.
__global__ __launch_bounds__(256) void recompute_kernel(
    const u16* __restrict__ spk_row, const float* __restrict__ w2,
    const float* __restrict__ maxv, const int* __restrict__ argm,
    int* __restrict__ winmap, float* __restrict__ potwin) {
  __shared__ u16 patch[30 * 18 * 18];

  int tid = threadIdx.x, b = blockIdx.x;
  int t = b / 25, tile = b % 25;
  int ty0 = (tile / 5) * 16, tx0 = (tile % 5) * 16;

  // u32 staging: patch[c][18][18] viewed as [c][18][9] u32 (all offsets even)
  const u16* base = spk_row + (size_t)t * 30 * 6724;
  unsigned* p32 = (unsigned*)patch;
  for (int idx = tid; idx < 4860; idx += 256) {
    int c = idx / 162, rem = idx % 162;
    int dy = rem / 9, dxp = rem % 9;
    p32[idx] = *(const unsigned*)(base + c * 6724 + (ty0 + dy) * 82 + tx0 +
                                  dxp * 2);
  }

  int py = tid >> 4, px = tid & 15;
  int pos = (ty0 + py) * 80 + tx0 + px;

  int nc = 0;
#pragma unroll
  for (int tt = 0; tt < T_STEPS; ++tt)
    nc += (maxv[tt * 6400 + pos] > 0.f) ? 1 : 0;
  int e = T_STEPS - nc; if (e > 14) e = 14;
  int win = argm[e * 6400 + pos];
  if (!(maxv[14 * 6400 + pos] > 0.f)) win = -1;
  if (t == 0) winmap[pos] = win;

  __syncthreads();

  float p = 0.f;
  if (win >= 0) {
    const float* wt = w2 + win * 270;
    float a = 0.f;
    for (int c = 0; c < 30; ++c) {        // exact fp32 chain (matches ref)
#pragma unroll
      for (int ky = 0; ky < 3; ++ky)
#pragma unroll
        for (int kx = 0; kx < 3; ++kx)
          a = fmaf(wt[c * 9 + ky * 3 + kx],
                   bf2f(patch[c * 324 + (py + ky) * 18 + (px + kx)]), a);
    }
    p = (a >= 10.f) ? a : 0.f;
  }
  potwin[t * 6400 + pos] = p;
}

// ---------------------------------------------------------------------------
// K4: block 0 = get_k_winners; blocks 1-25 = sparse scatter into zeroed d_out
__global__ __launch_bounds__(1024) void finalize_kernel(
    const int* __restrict__ winmap, const float* __restrict__ potwin,
    float* __restrict__ out, float* __restrict__ out_win) {
  __shared__ float tv[6400];
  __shared__ int   tf[6400];
  __shared__ float wv_s[16];
  __shared__ int   wk_s[16];
  __shared__ int   sh_w[4];
  __shared__ float vmax_s;

  int tid = threadIdx.x;
  int b = blockIdx.x;

  if (b > 0) {
    int pos = (b - 1) * 256 + (tid & 255);
    int tq = tid >> 8;
    int win = winmap[pos];
    if (win < 0) return;
    int tend = tq * 4 + 4; if (tend > T_STEPS) tend = T_STEPS;
    for (int t = tq * 4; t < tend; ++t) {
      float p = potwin[t * 6400 + pos];
      int o = (t * 250 + win) * 6400 + pos;
      out[o] = (p > 0.f) ? 1.f : 0.f;
      out[24000000 + o] = p;
    }
    return;
  }

  int lane = tid & 63, wid = tid >> 6;

  float localmax = 0.f;
  for (int pos = tid; pos < 6400; pos += 1024) {
    int win = winmap[pos];
    float val = 0.f; int nspk = 0;
    if (win >= 0) {
#pragma unroll
      for (int t = 0; t < T_STEPS; ++t)
        nspk += (potwin[t * 6400 + pos] > 0.f) ? 1 : 0;
      int first = T_STEPS - nspk; if (first > 14) first = 14;
      val = potwin[first * 6400 + pos];
      if (nspk > 0 && val > localmax) localmax = val;
    }
    tv[pos] = val;
    tf[pos] = ((win + 1) << 4) | nspk;
  }
#pragma unroll
  for (int m = 1; m < 64; m <<= 1)
    localmax = fmaxf(localmax, __shfl_xor(localmax, m));
  if (lane == 0) wv_s[wid] = localmax;
  __syncthreads();
  if (tid == 0) {
    float m = 0.f;
#pragma unroll
    for (int w = 0; w < 16; ++w) m = fmaxf(m, wv_s[w]);
    vmax_s = m * (float)T_STEPS;
  }
  __syncthreads();
  float v = vmax_s;

  for (int pos = tid; pos < 6400; pos += 1024) {
    int meta = tf[pos];
    int win = (meta >> 4) - 1, nspk = meta & 15;
    tf[pos] = win;
    tv[pos] = (win >= 0) ? (float)nspk * (tv[pos] + v) : 0.f;
  }
  __syncthreads();

  for (int it = 0; it < 8; ++it) {
    float bv = -1.f; int bk = 0x7fffffff;
    for (int pos = tid; pos < 6400; pos += 1024) {
      float tvv = tv[pos];
      int key = tf[pos] * 6400 + pos;
      if (tvv > bv || (tvv == bv && key < bk)) { bv = tvv; bk = key; }
    }
#pragma unroll
    for (int m = 1; m < 64; m <<= 1) {
      float ov = __shfl_xor(bv, m); int ok = __shfl_xor(bk, m);
      if (ov > bv || (ov == bv && ok < bk)) { bv = ov; bk = ok; }
    }
    if (lane == 0) { wv_s[wid] = bv; wk_s[wid] = bk; }
    __syncthreads();
    if (tid == 0) {
      float mbv = -1.f; int mbk = 0x7fffffff;
#pragma unroll
      for (int w = 0; w < 16; ++w) {
        float ov = wv_s[w]; int ok = wk_s[w];
        if (ov > mbv || (ov == mbv && ok < mbk)) { mbv = ov; mbk = ok; }
      }
      int f = -1, r = -1, c = -1, valid = 0;
      if (mbv != 0.f) {
        f = mbk / 6400; int pos = mbk % 6400;
        r = pos / 80; c = pos % 80;
        valid = 1;
      }
      out_win[it * 3 + 0] = (float)f;
      out_win[it * 3 + 1] = (float)r;
      out_win[it * 3 + 2] = (float)c;
      sh_w[0] = f; sh_w[1] = r; sh_w[2] = c; sh_w[3] = valid;
    }
    __syncthreads();
    if (sh_w[3]) {
      int wf = sh_w[0], wr = sh_w[1], wc = sh_w[2];
      for (int pos = tid; pos < 6400; pos += 1024) {
        int r = pos / 80, c = pos % 80;
        int dr = r - wr; if (dr < 0) dr = -dr;
        int dc = c - wc; if (dc < 0) dc = -dc;
        if (tf[pos] == wf || (dr <= 1 && dc <= 1)) tv[pos] = 0.f;
      }
    }
    __syncthreads();
  }
}

// ---------------------------------------------------------------------------
extern "C" void kernel_launch(void* const* d_in, const int* in_sizes, int n_in,
                              void* d_out, int out_size, void* d_ws,
                              size_t ws_size, hipStream_t stream) {
  const int*   xin = (const int*)d_in[0];
  const float* w1  = (const float*)d_in[1];
  const float* w2  = (const float*)d_in[2];
  float* out = (float*)d_out;
  char*  ws  = (char*)d_ws;

  u16*   inp_cl  = (u16*)(ws + INPCL_OFF);
  u16*   spk_cl  = (u16*)(ws + SPKCL_OFF);
  u16*   spk_row = (u16*)(ws + SPKROW_OFF);
  u16*   w1cl    = (u16*)(ws + W1CL_OFF);
  u16*   Whi     = (u16*)(ws + WHI_OFF);
  u16*   Wlo     = (u16*)(ws + WLO_OFF);
  float* maxv    = (float*)(ws + MAXV_OFF);
  int*   argm    = (int*)(ws + ARGM_OFF);
  int*   winmap  = (int*)(ws + WINMAP_OFF);
  float* potwin  = (float*)(ws + POTWIN_OFF);

  prep_kernel<<<K1A_GRID, 256, 0, stream>>>(xin, w1, w2, inp_cl, w1cl, Whi,
                                            Wlo, spk_cl, spk_row);
  conv1_fill_kernel<<<K1B_GRID, 256, 0, stream>>>(inp_cl, w1cl, spk_cl,
                                                  spk_row, (float4v*)d_out,
                                                  out_size / 4);
  conv2_kernel<<<1500, 512, 0, stream>>>(spk_cl, Whi, Wlo, maxv, argm);
  recompute_kernel<<<375, 256, 0, stream>>>(spk_row, w2, maxv, argm, winmap,
                                            potwin);
  finalize_kernel<<<26, 1024, 0, stream>>>(winmap, potwin, out,
                                           out + 48000000);
}